// Round 21
// baseline (19.511 us; speedup 1.0000x reference)
//
#include <hip/hip_runtime.h>
#include <math.h>

#define L 512
#define NTHREADS 512      // 8 waves; each wave owns a 32-d column slice
#define BLOCK_TT 32       // two 16-t sub-tiles; shared prologue AND shared B-gather
#define ZWIN 9.0f         // dropped pdf mass <= exp(-40.5): < 1e-10 effect on output
#define NXCD 8

typedef __attribute__((ext_vector_type(8))) short bf16x8;
typedef __attribute__((ext_vector_type(4))) float f32x4;

static constexpr float EPS = 1e-6f;
static constexpr float INV_SQRT_2PI = 0.39894228040143267794f;

union BFrag { unsigned int u[4]; bf16x8 h; };

__global__ __launch_bounds__(NTHREADS, 8) void ge_mfma(
    const int*   __restrict__ durs,  // [B, L]
    const float* __restrict__ text,  // [B, L, 256]
    float*       __restrict__ out,   // [B, T, 256]
    int B, int T, int tilesPerB, int nwg)
{
    __shared__ float2 s_mi[L];

    const int tid  = threadIdx.x;
    const int lane = tid & 63;
    const int wid  = tid >> 6;       // 0..7, owns d-cols [wid*32, wid*32+32)
    const int g    = lane >> 4;      // k-group (A/B), C row-group
    const int mrow = lane & 15;      // A-row (t offset) == B/C-col (d offset)

    const int orig = blockIdx.x;
    const int wg   = (nwg % NXCD == 0) ? (orig & (NXCD - 1)) * (nwg / NXCD) + (orig >> 3)
                                       : orig;
    const int b      = wg / tilesPerB;
    const int tbase0 = (wg % tilesPerB) * BLOCK_TT;

    // ---- wave-private scan, once per wave: lane owns rows 8*lane..8*lane+7 ----
    const int r0 = lane << 3;
    const int4 da = ((const int4*)(durs + (size_t)b * L + r0))[0];
    const int4 db = ((const int4*)(durs + (size_t)b * L + r0))[1];
    int dv[8] = {da.x, da.y, da.z, da.w, db.x, db.y, db.z, db.w};
    int cs[8];
    int run = 0;
    #pragma unroll
    for (int j = 0; j < 8; ++j) { run += dv[j]; cs[j] = run; }
    int v = run;
    #pragma unroll
    for (int off = 1; off < 64; off <<= 1) {
        int n = __shfl_up(v, off, 64);
        if (lane >= off) v += n;
    }
    const int excl = v - run;

    // ---- params to LDS (all waves write identical values) + UNION band ----
    const float tlo = (float)tbase0 + 0.5f;
    const float thi = (float)tbase0 + (float)BLOCK_TT - 0.5f;
    int mn = L, mx = -1;
    #pragma unroll
    for (int j = 0; j < 8; ++j) {
        const float d  = (float)dv[j];
        const float m  = (float)(cs[j] + excl) + 0.5f * d;
        const float sg = 0.5f * d + EPS;
        s_mi[r0 + j] = make_float2(m, 1.0f / sg);
        const float r = ZWIN * sg;
        if (dv[j] >= 1 && m + r >= tlo && m - r <= thi) {
            mn = min(mn, r0 + j);
            mx = max(mx, r0 + j);
        }
    }
    #pragma unroll
    for (int off = 32; off > 0; off >>= 1) {
        mn = min(mn, __shfl_xor(mn, off, 64));
        mx = max(mx, __shfl_xor(mx, off, 64));
    }
    asm volatile("s_waitcnt lgkmcnt(0)" ::: "memory");   // own-wave s_mi writes -> reads
    __builtin_amdgcn_sched_barrier(0);

    // ---- main loop over union band: wave covers 2 col-tiles x both 16-t halves ----
    f32x4 a00 = {0,0,0,0}, a01 = {0,0,0,0};   // half 0, nt 0/1
    f32x4 a10 = {0,0,0,0}, a11 = {0,0,0,0};   // half 1
    float psum0 = 0.f, psum1 = 0.f;
    const float tf0 = (float)(tbase0 + mrow) + 0.5f;
    const float tf1 = tf0 + 16.f;
    const float* tbp = text + (size_t)b * L * 256 + (wid << 5) + mrow;

    for (int kb = (mn & ~7); kb <= mx; kb += 32) {
        const int k0 = kb + (g << 3);

        // A fragments for both halves; psum on fp32 pre-round
        BFrag A0, A1;
        #pragma unroll
        for (int jp = 0; jp < 4; ++jp) {
            const int ka = k0 + 2 * jp;
            const int kc = ka + 1;
            const float2 mia = s_mi[ka & (L - 1)];
            const float2 mic = s_mi[kc & (L - 1)];
            const float ca = mia.y * INV_SQRT_2PI;
            const float cc = mic.y * INV_SQRT_2PI;
            const float u0a = (tf0 - mia.x) * mia.y;
            const float u0c = (tf0 - mic.x) * mic.y;
            const float u1a = (tf1 - mia.x) * mia.y;
            const float u1c = (tf1 - mic.x) * mic.y;
            float p0a = __expf(-0.5f * u0a * u0a) * ca;
            float p0c = __expf(-0.5f * u0c * u0c) * cc;
            float p1a = __expf(-0.5f * u1a * u1a) * ca;
            float p1c = __expf(-0.5f * u1c * u1c) * cc;
            p0a = (ka <= mx) ? p0a : 0.f;  p1a = (ka <= mx) ? p1a : 0.f;
            p0c = (kc <= mx) ? p0c : 0.f;  p1c = (kc <= mx) ? p1c : 0.f;
            psum0 += p0a + p0c;
            psum1 += p1a + p1c;
            asm("v_cvt_pk_bf16_f32 %0, %1, %2" : "=v"(A0.u[jp]) : "v"(p0a), "v"(p0c));
            asm("v_cvt_pk_bf16_f32 %0, %1, %2" : "=v"(A1.u[jp]) : "v"(p1a), "v"(p1c));
        }

        // B fragments: 2 col-tiles for this wave's 32-d slice
        BFrag B0, B1;
        #pragma unroll
        for (int jp = 0; jp < 4; ++jp) {
            const int ka = min(k0 + 2 * jp,     L - 1);   // p==0 past mx: garbage*0 == 0
            const int kc = min(k0 + 2 * jp + 1, L - 1);
            const float* ra = tbp + (size_t)ka * 256;
            const float* rc = tbp + (size_t)kc * 256;
            const float b0 = ra[0], b1 = ra[16];
            const float c0 = rc[0], c1 = rc[16];
            asm("v_cvt_pk_bf16_f32 %0, %1, %2" : "=v"(B0.u[jp]) : "v"(b0), "v"(c0));
            asm("v_cvt_pk_bf16_f32 %0, %1, %2" : "=v"(B1.u[jp]) : "v"(b1), "v"(c1));
        }

        a00 = __builtin_amdgcn_mfma_f32_16x16x32_bf16(A0.h, B0.h, a00, 0, 0, 0);
        a01 = __builtin_amdgcn_mfma_f32_16x16x32_bf16(A0.h, B1.h, a01, 0, 0, 0);
        a10 = __builtin_amdgcn_mfma_f32_16x16x32_bf16(A1.h, B0.h, a10, 0, 0, 0);
        a11 = __builtin_amdgcn_mfma_f32_16x16x32_bf16(A1.h, B1.h, a11, 0, 0, 0);
    }

    // ---- epilogue per half: shuffle-reduced denominators, normalize, store ----
    const int trow = g << 2;
    #pragma unroll
    for (int half = 0; half < 2; ++half) {
        float ps = half ? psum1 : psum0;
        ps += __shfl_xor(ps, 16, 64);
        ps += __shfl_xor(ps, 32, 64);
        const float rn = 1.0f / (ps + EPS);   // lane (g,mrow): denom for t = t0+mrow

        const float rr0 = __shfl(rn, trow + 0, 64);
        const float rr1 = __shfl(rn, trow + 1, 64);
        const float rr2 = __shfl(rn, trow + 2, 64);
        const float rr3 = __shfl(rn, trow + 3, 64);

        const f32x4 c0 = half ? a10 : a00;
        const f32x4 c1 = half ? a11 : a01;

        const int t0 = tbase0 + (half << 4);
        float* ob = out + ((size_t)b * T + t0 + trow) * 256 + (wid << 5) + mrow;
        if (t0 + trow + 3 < T) {
            ob[0*256 +  0] = c0[0] * rr0;  ob[1*256 +  0] = c0[1] * rr1;
            ob[2*256 +  0] = c0[2] * rr2;  ob[3*256 +  0] = c0[3] * rr3;
            ob[0*256 + 16] = c1[0] * rr0;  ob[1*256 + 16] = c1[1] * rr1;
            ob[2*256 + 16] = c1[2] * rr2;  ob[3*256 + 16] = c1[3] * rr3;
        }
    }
}

extern "C" void kernel_launch(void* const* d_in, const int* in_sizes, int n_in,
                              void* d_out, int out_size, void* d_ws, size_t ws_size,
                              hipStream_t stream) {
    const int*   durs = (const int*)d_in[1];
    const float* text = (const float*)d_in[0];
    float*       out  = (float*)d_out;

    const int BL = in_sizes[1];        // B * L
    const int D  = in_sizes[0] / BL;   // 256
    const int B  = BL / L;             // 16
    const int T  = out_size / (B * D); // 2048
    const int tilesPerB = (T + BLOCK_TT - 1) / BLOCK_TT;   // 64
    const int nwg = B * tilesPerB;     // 1024

    ge_mfma<<<dim3(nwg), dim3(NTHREADS), 0, stream>>>(durs, text, out, B, T, tilesPerB, nwg);
}

// Round 23
// 16.918 us; speedup vs baseline: 1.1533x; 1.1533x over previous
//
#include <hip/hip_runtime.h>
#include <math.h>

#define L 512
#define NTHREADS 256
#define BLOCK_TT 32       // two 16-t sub-tiles; shared prologue AND shared B-gather
#define ZWIN 9.0f         // dropped pdf mass <= exp(-40.5): < 1e-10 effect on output
#define NXCD 8

typedef __attribute__((ext_vector_type(8))) short bf16x8;
typedef __attribute__((ext_vector_type(4))) float f32x4;

static constexpr float EPS2  = 2.50662827e-6f;   // 1e-6 * sqrt(2*pi) (INV_SQRT_2PI cancelled)
static constexpr float KLOG  = -0.72134752f;     // -log2(e)/2

union BFrag { unsigned int u[4]; bf16x8 h; };

__global__ __launch_bounds__(NTHREADS, 4) void ge_mfma(
    const int*   __restrict__ durs,  // [B, L]
    const float* __restrict__ text,  // [B, L, 256]
    float*       __restrict__ out,   // [B, T, 256]
    int B, int T, int tilesPerB, int nwg)
{
    __shared__ float4 s_mi[L];       // (isig, mi = m*isig, lg = log2(isig), 0)

    const int tid  = threadIdx.x;
    const int lane = tid & 63;
    const int wid  = tid >> 6;
    const int g    = lane >> 4;      // k-group (A/B), C row-group
    const int mrow = lane & 15;      // A-row (t offset) == B/C-col (d offset)

    const int orig = blockIdx.x;
    const int wg   = (nwg % NXCD == 0) ? (orig & (NXCD - 1)) * (nwg / NXCD) + (orig >> 3)
                                       : orig;
    const int b      = wg / tilesPerB;
    const int tbase0 = (wg % tilesPerB) * BLOCK_TT;

    // ---- wave-private scan, once per block: lane owns rows 8*lane..8*lane+7 ----
    const int r0 = lane << 3;
    const int4 da = ((const int4*)(durs + (size_t)b * L + r0))[0];
    const int4 db = ((const int4*)(durs + (size_t)b * L + r0))[1];
    int dv[8] = {da.x, da.y, da.z, da.w, db.x, db.y, db.z, db.w};
    int cs[8];
    int run = 0;
    #pragma unroll
    for (int j = 0; j < 8; ++j) { run += dv[j]; cs[j] = run; }
    int v = run;
    #pragma unroll
    for (int off = 1; off < 64; off <<= 1) {
        int n = __shfl_up(v, off, 64);
        if (lane >= off) v += n;
    }
    const int excl = v - run;

    // ---- params to LDS + UNION band over the 32-t block ----
    const float tlo = (float)tbase0 + 0.5f;
    const float thi = (float)tbase0 + (float)BLOCK_TT - 0.5f;
    int mn = L, mx = -1;
    #pragma unroll
    for (int j = 0; j < 8; ++j) {
        const float d  = (float)dv[j];
        const float m  = (float)(cs[j] + excl) + 0.5f * d;
        const float sg = 0.5f * d + 1e-6f;
        const float isig = 1.0f / sg;
        const float mi   = m * isig;
        const float lg   = log2f(isig);
        s_mi[r0 + j] = make_float4(isig, mi, lg, 0.f);
        const float r = ZWIN * sg;
        if (dv[j] >= 1 && m + r >= tlo && m - r <= thi) {
            mn = min(mn, r0 + j);
            mx = max(mx, r0 + j);
        }
    }
    #pragma unroll
    for (int off = 32; off > 0; off >>= 1) {
        mn = min(mn, __shfl_xor(mn, off, 64));
        mx = max(mx, __shfl_xor(mx, off, 64));
    }
    asm volatile("s_waitcnt lgkmcnt(0)" ::: "memory");   // own-wave s_mi writes -> reads
    __builtin_amdgcn_sched_barrier(0);

    // ---- main loop over union band: ONE B-gather feeds BOTH 16-t halves ----
    f32x4 a00 = {0,0,0,0}, a01 = {0,0,0,0}, a02 = {0,0,0,0}, a03 = {0,0,0,0};  // half 0
    f32x4 a10 = {0,0,0,0}, a11 = {0,0,0,0}, a12 = {0,0,0,0}, a13 = {0,0,0,0};  // half 1
    float psum0 = 0.f, psum1 = 0.f;
    const float tf0 = (float)(tbase0 + mrow) + 0.5f;    // half0's t for this lane
    const float tf1 = tf0 + 16.f;                       // half1's t
    const float* tbp = text + (size_t)b * L * 256 + (wid << 6) + mrow;

    for (int kb = (mn & ~7); kb <= mx; kb += 32) {
        const int k0 = kb + (g << 3);

        // A fragments for both halves: p = exp2(K*u^2 + lg), u = fma(t, isig, -mi)
        BFrag A0, A1;
        #pragma unroll
        for (int jp = 0; jp < 4; ++jp) {
            const int ka = k0 + 2 * jp;
            const int kc = ka + 1;
            const float4 pa = s_mi[ka & (L - 1)];
            const float4 pc = s_mi[kc & (L - 1)];
            const float u0a = fmaf(tf0, pa.x, -pa.y);
            const float u0c = fmaf(tf0, pc.x, -pc.y);
            const float u1a = fmaf(tf1, pa.x, -pa.y);
            const float u1c = fmaf(tf1, pc.x, -pc.y);
            float p0a = exp2f(fmaf(u0a * u0a, KLOG, pa.z));
            float p0c = exp2f(fmaf(u0c * u0c, KLOG, pc.z));
            float p1a = exp2f(fmaf(u1a * u1a, KLOG, pa.z));
            float p1c = exp2f(fmaf(u1c * u1c, KLOG, pc.z));
            p0a = (ka <= mx) ? p0a : 0.f;  p1a = (ka <= mx) ? p1a : 0.f;
            p0c = (kc <= mx) ? p0c : 0.f;  p1c = (kc <= mx) ? p1c : 0.f;
            psum0 += p0a + p0c;
            psum1 += p1a + p1c;
            asm("v_cvt_pk_bf16_f32 %0, %1, %2" : "=v"(A0.u[jp]) : "v"(p0a), "v"(p0c));
            asm("v_cvt_pk_bf16_f32 %0, %1, %2" : "=v"(A1.u[jp]) : "v"(p1a), "v"(p1c));
        }

        // B fragments: ONE gather, shared by both halves
        BFrag B0, B1, B2, B3;
        #pragma unroll
        for (int jp = 0; jp < 4; ++jp) {
            const int ka = min(k0 + 2 * jp,     L - 1);   // p==0 past mx: garbage*0 == 0
            const int kc = min(k0 + 2 * jp + 1, L - 1);
            const float* ra = tbp + (size_t)ka * 256;
            const float* rc = tbp + (size_t)kc * 256;
            const float b0 = ra[0], b1 = ra[16], b2 = ra[32], b3 = ra[48];
            const float c0 = rc[0], c1 = rc[16], c2 = rc[32], c3 = rc[48];
            asm("v_cvt_pk_bf16_f32 %0, %1, %2" : "=v"(B0.u[jp]) : "v"(b0), "v"(c0));
            asm("v_cvt_pk_bf16_f32 %0, %1, %2" : "=v"(B1.u[jp]) : "v"(b1), "v"(c1));
            asm("v_cvt_pk_bf16_f32 %0, %1, %2" : "=v"(B2.u[jp]) : "v"(b2), "v"(c2));
            asm("v_cvt_pk_bf16_f32 %0, %1, %2" : "=v"(B3.u[jp]) : "v"(b3), "v"(c3));
        }

        a00 = __builtin_amdgcn_mfma_f32_16x16x32_bf16(A0.h, B0.h, a00, 0, 0, 0);
        a01 = __builtin_amdgcn_mfma_f32_16x16x32_bf16(A0.h, B1.h, a01, 0, 0, 0);
        a02 = __builtin_amdgcn_mfma_f32_16x16x32_bf16(A0.h, B2.h, a02, 0, 0, 0);
        a03 = __builtin_amdgcn_mfma_f32_16x16x32_bf16(A0.h, B3.h, a03, 0, 0, 0);
        a10 = __builtin_amdgcn_mfma_f32_16x16x32_bf16(A1.h, B0.h, a10, 0, 0, 0);
        a11 = __builtin_amdgcn_mfma_f32_16x16x32_bf16(A1.h, B1.h, a11, 0, 0, 0);
        a12 = __builtin_amdgcn_mfma_f32_16x16x32_bf16(A1.h, B2.h, a12, 0, 0, 0);
        a13 = __builtin_amdgcn_mfma_f32_16x16x32_bf16(A1.h, B3.h, a13, 0, 0, 0);
    }

    // ---- epilogue per half: shuffle-reduced denominators, normalize, store ----
    const int trow = g << 2;
    #pragma unroll
    for (int half = 0; half < 2; ++half) {
        float ps = half ? psum1 : psum0;
        ps += __shfl_xor(ps, 16, 64);
        ps += __shfl_xor(ps, 32, 64);
        const float rn = 1.0f / (ps + EPS2);

        const float rr0 = __shfl(rn, trow + 0, 64);
        const float rr1 = __shfl(rn, trow + 1, 64);
        const float rr2 = __shfl(rn, trow + 2, 64);
        const float rr3 = __shfl(rn, trow + 3, 64);

        const f32x4 c0 = half ? a10 : a00;
        const f32x4 c1 = half ? a11 : a01;
        const f32x4 c2 = half ? a12 : a02;
        const f32x4 c3 = half ? a13 : a03;

        const int t0 = tbase0 + (half << 4);
        float* ob = out + ((size_t)b * T + t0 + trow) * 256 + (wid << 6) + mrow;
        if (t0 + trow + 3 < T) {
            ob[0*256 +  0] = c0[0] * rr0;  ob[1*256 +  0] = c0[1] * rr1;
            ob[2*256 +  0] = c0[2] * rr2;  ob[3*256 +  0] = c0[3] * rr3;
            ob[0*256 + 16] = c1[0] * rr0;  ob[1*256 + 16] = c1[1] * rr1;
            ob[2*256 + 16] = c1[2] * rr2;  ob[3*256 + 16] = c1[3] * rr3;
            ob[0*256 + 32] = c2[0] * rr0;  ob[1*256 + 32] = c2[1] * rr1;
            ob[2*256 + 32] = c2[2] * rr2;  ob[3*256 + 32] = c2[3] * rr3;
            ob[0*256 + 48] = c3[0] * rr0;  ob[1*256 + 48] = c3[1] * rr1;
            ob[2*256 + 48] = c3[2] * rr2;  ob[3*256 + 48] = c3[3] * rr3;
        }
    }
}

extern "C" void kernel_launch(void* const* d_in, const int* in_sizes, int n_in,
                              void* d_out, int out_size, void* d_ws, size_t ws_size,
                              hipStream_t stream) {
    const int*   durs = (const int*)d_in[1];
    const float* text = (const float*)d_in[0];
    float*       out  = (float*)d_out;

    const int BL = in_sizes[1];        // B * L
    const int D  = in_sizes[0] / BL;   // 256
    const int B  = BL / L;             // 16
    const int T  = out_size / (B * D); // 2048
    const int tilesPerB = (T + BLOCK_TT - 1) / BLOCK_TT;   // 64
    const int nwg = B * tilesPerB;     // 1024

    ge_mfma<<<dim3(nwg), dim3(NTHREADS), 0, stream>>>(durs, text, out, B, T, tilesPerB, nwg);
}

// Round 24
// 14.582 us; speedup vs baseline: 1.3380x; 1.1602x over previous
//
#include <hip/hip_runtime.h>
#include <math.h>

#define L 512
#define LPAD 544          // s_mi padded: rows 512..543 = {0,0} -> p==0 naturally
#define NTHREADS 256
#define BLOCK_TT 32       // two 16-t sub-tiles; shared prologue AND shared B-gather
#define ZWIN 9.0f         // dropped pdf mass <= exp(-40.5): < 1e-10 effect on output
#define NXCD 8

typedef __attribute__((ext_vector_type(8))) short bf16x8;
typedef __attribute__((ext_vector_type(4))) float f32x4;

static constexpr float EPS = 1e-6f;
static constexpr float INV_SQRT_2PI = 0.39894228040143267794f;

union BFrag { unsigned int u[4]; bf16x8 h; };

__global__ __launch_bounds__(NTHREADS, 4) void ge_mfma(
    const int*   __restrict__ durs,  // [B, L]
    const float* __restrict__ text,  // [B, L, 256]
    float*       __restrict__ out,   // [B, T, 256]
    int B, int T, int tilesPerB, int nwg)
{
    __shared__ float2 s_mi[LPAD];

    const int tid  = threadIdx.x;
    const int lane = tid & 63;
    const int wid  = tid >> 6;
    const int g    = lane >> 4;      // k-group (A/B), C row-group
    const int mrow = lane & 15;      // A-row (t offset) == B/C-col (d offset)

    const int orig = blockIdx.x;
    const int wg   = (nwg % NXCD == 0) ? (orig & (NXCD - 1)) * (nwg / NXCD) + (orig >> 3)
                                       : orig;
    const int b      = wg / tilesPerB;
    const int tbase0 = (wg % tilesPerB) * BLOCK_TT;

    // ---- wave-private scan, once per block: lane owns rows 8*lane..8*lane+7 ----
    const int r0 = lane << 3;
    const int4 da = ((const int4*)(durs + (size_t)b * L + r0))[0];
    const int4 db = ((const int4*)(durs + (size_t)b * L + r0))[1];
    int dv[8] = {da.x, da.y, da.z, da.w, db.x, db.y, db.z, db.w};
    int cs[8];
    int run = 0;
    #pragma unroll
    for (int j = 0; j < 8; ++j) { run += dv[j]; cs[j] = run; }
    int v = run;
    #pragma unroll
    for (int off = 1; off < 64; off <<= 1) {
        int n = __shfl_up(v, off, 64);
        if (lane >= off) v += n;
    }
    const int excl = v - run;

    // ---- params to LDS (+ zero pads) + UNION band over the 32-t block ----
    const float tlo = (float)tbase0 + 0.5f;
    const float thi = (float)tbase0 + (float)BLOCK_TT - 0.5f;
    int mn = L, mx = -1;
    #pragma unroll
    for (int j = 0; j < 8; ++j) {
        const float d  = (float)dv[j];
        const float m  = (float)(cs[j] + excl) + 0.5f * d;
        const float sg = 0.5f * d + EPS;
        s_mi[r0 + j] = make_float2(m, 1.0f / sg);
        const float r = ZWIN * sg;
        if (dv[j] >= 1 && m + r >= tlo && m - r <= thi) {
            mn = min(mn, r0 + j);
            mx = max(mx, r0 + j);
        }
    }
    if (lane < LPAD - L) s_mi[L + lane] = make_float2(0.f, 0.f);  // isig==0 -> p==0
    #pragma unroll
    for (int off = 32; off > 0; off >>= 1) {
        mn = min(mn, __shfl_xor(mn, off, 64));
        mx = max(mx, __shfl_xor(mx, off, 64));
    }
    asm volatile("s_waitcnt lgkmcnt(0)" ::: "memory");   // own-wave s_mi writes -> reads
    __builtin_amdgcn_sched_barrier(0);

    // ---- main loop over union band: ONE B-gather feeds BOTH 16-t halves ----
    f32x4 a00 = {0,0,0,0}, a01 = {0,0,0,0}, a02 = {0,0,0,0}, a03 = {0,0,0,0};  // half 0
    f32x4 a10 = {0,0,0,0}, a11 = {0,0,0,0}, a12 = {0,0,0,0}, a13 = {0,0,0,0};  // half 1
    float psum0 = 0.f, psum1 = 0.f;
    const float tf0 = (float)(tbase0 + mrow) + 0.5f;    // half0's t for this lane
    const float tf1 = tf0 + 16.f;                       // half1's t
    const float* tbp = text + (size_t)b * L * 256 + (wid << 6) + mrow;

    for (int kb = (mn & ~7); kb <= mx; kb += 32) {
        const int k0 = kb + (g << 3);

        // B fragments FIRST: issue the 32 independent loads under the A-exp chain
        BFrag B0, B1, B2, B3;
        #pragma unroll
        for (int jp = 0; jp < 4; ++jp) {
            const int ka = min(k0 + 2 * jp,     L - 1);   // p==0 past L-1: garbage*0 == 0
            const int kc = min(k0 + 2 * jp + 1, L - 1);
            const float* ra = tbp + (size_t)ka * 256;
            const float* rc = tbp + (size_t)kc * 256;
            const float b0 = ra[0], b1 = ra[16], b2 = ra[32], b3 = ra[48];
            const float c0 = rc[0], c1 = rc[16], c2 = rc[32], c3 = rc[48];
            asm("v_cvt_pk_bf16_f32 %0, %1, %2" : "=v"(B0.u[jp]) : "v"(b0), "v"(c0));
            asm("v_cvt_pk_bf16_f32 %0, %1, %2" : "=v"(B1.u[jp]) : "v"(b1), "v"(c1));
            asm("v_cvt_pk_bf16_f32 %0, %1, %2" : "=v"(B2.u[jp]) : "v"(b2), "v"(c2));
            asm("v_cvt_pk_bf16_f32 %0, %1, %2" : "=v"(B3.u[jp]) : "v"(b3), "v"(c3));
        }

        // A fragments for both halves (no selects; pads/d==0 underflow to 0 naturally)
        BFrag A0, A1;
        #pragma unroll
        for (int jp = 0; jp < 4; ++jp) {
            const int ka = k0 + 2 * jp;          // <= mx+31 <= 542 < LPAD
            const int kc = ka + 1;
            const float2 mia = s_mi[ka];
            const float2 mic = s_mi[kc];
            const float ca = mia.y * INV_SQRT_2PI;
            const float cc = mic.y * INV_SQRT_2PI;
            const float u0a = (tf0 - mia.x) * mia.y;
            const float u0c = (tf0 - mic.x) * mic.y;
            const float u1a = (tf1 - mia.x) * mia.y;
            const float u1c = (tf1 - mic.x) * mic.y;
            const float p0a = __expf(-0.5f * u0a * u0a) * ca;
            const float p0c = __expf(-0.5f * u0c * u0c) * cc;
            const float p1a = __expf(-0.5f * u1a * u1a) * ca;
            const float p1c = __expf(-0.5f * u1c * u1c) * cc;
            psum0 += p0a + p0c;
            psum1 += p1a + p1c;
            asm("v_cvt_pk_bf16_f32 %0, %1, %2" : "=v"(A0.u[jp]) : "v"(p0a), "v"(p0c));
            asm("v_cvt_pk_bf16_f32 %0, %1, %2" : "=v"(A1.u[jp]) : "v"(p1a), "v"(p1c));
        }

        a00 = __builtin_amdgcn_mfma_f32_16x16x32_bf16(A0.h, B0.h, a00, 0, 0, 0);
        a01 = __builtin_amdgcn_mfma_f32_16x16x32_bf16(A0.h, B1.h, a01, 0, 0, 0);
        a02 = __builtin_amdgcn_mfma_f32_16x16x32_bf16(A0.h, B2.h, a02, 0, 0, 0);
        a03 = __builtin_amdgcn_mfma_f32_16x16x32_bf16(A0.h, B3.h, a03, 0, 0, 0);
        a10 = __builtin_amdgcn_mfma_f32_16x16x32_bf16(A1.h, B0.h, a10, 0, 0, 0);
        a11 = __builtin_amdgcn_mfma_f32_16x16x32_bf16(A1.h, B1.h, a11, 0, 0, 0);
        a12 = __builtin_amdgcn_mfma_f32_16x16x32_bf16(A1.h, B2.h, a12, 0, 0, 0);
        a13 = __builtin_amdgcn_mfma_f32_16x16x32_bf16(A1.h, B3.h, a13, 0, 0, 0);
    }

    // ---- epilogue per half: shuffle-reduced denominators, normalize, nt-store ----
    const int trow = g << 2;
    #pragma unroll
    for (int half = 0; half < 2; ++half) {
        float ps = half ? psum1 : psum0;
        ps += __shfl_xor(ps, 16, 64);
        ps += __shfl_xor(ps, 32, 64);
        const float rn = 1.0f / (ps + EPS);   // lane (g,mrow): denom for t = t0+mrow

        const float rr0 = __shfl(rn, trow + 0, 64);
        const float rr1 = __shfl(rn, trow + 1, 64);
        const float rr2 = __shfl(rn, trow + 2, 64);
        const float rr3 = __shfl(rn, trow + 3, 64);

        const f32x4 c0 = half ? a10 : a00;
        const f32x4 c1 = half ? a11 : a01;
        const f32x4 c2 = half ? a12 : a02;
        const f32x4 c3 = half ? a13 : a03;

        const int t0 = tbase0 + (half << 4);
        float* ob = out + ((size_t)b * T + t0 + trow) * 256 + (wid << 6) + mrow;
        if (t0 + trow + 3 < T) {
            __builtin_nontemporal_store(c0[0] * rr0, ob + 0*256 +  0);
            __builtin_nontemporal_store(c0[1] * rr1, ob + 1*256 +  0);
            __builtin_nontemporal_store(c0[2] * rr2, ob + 2*256 +  0);
            __builtin_nontemporal_store(c0[3] * rr3, ob + 3*256 +  0);
            __builtin_nontemporal_store(c1[0] * rr0, ob + 0*256 + 16);
            __builtin_nontemporal_store(c1[1] * rr1, ob + 1*256 + 16);
            __builtin_nontemporal_store(c1[2] * rr2, ob + 2*256 + 16);
            __builtin_nontemporal_store(c1[3] * rr3, ob + 3*256 + 16);
            __builtin_nontemporal_store(c2[0] * rr0, ob + 0*256 + 32);
            __builtin_nontemporal_store(c2[1] * rr1, ob + 1*256 + 32);
            __builtin_nontemporal_store(c2[2] * rr2, ob + 2*256 + 32);
            __builtin_nontemporal_store(c2[3] * rr3, ob + 3*256 + 32);
            __builtin_nontemporal_store(c3[0] * rr0, ob + 0*256 + 48);
            __builtin_nontemporal_store(c3[1] * rr1, ob + 1*256 + 48);
            __builtin_nontemporal_store(c3[2] * rr2, ob + 2*256 + 48);
            __builtin_nontemporal_store(c3[3] * rr3, ob + 3*256 + 48);
        }
    }
}

extern "C" void kernel_launch(void* const* d_in, const int* in_sizes, int n_in,
                              void* d_out, int out_size, void* d_ws, size_t ws_size,
                              hipStream_t stream) {
    const int*   durs = (const int*)d_in[1];
    const float* text = (const float*)d_in[0];
    float*       out  = (float*)d_out;

    const int BL = in_sizes[1];        // B * L
    const int D  = in_sizes[0] / BL;   // 256
    const int B  = BL / L;             // 16
    const int T  = out_size / (B * D); // 2048
    const int tilesPerB = (T + BLOCK_TT - 1) / BLOCK_TT;   // 64
    const int nwg = B * tilesPerB;     // 1024

    ge_mfma<<<dim3(nwg), dim3(NTHREADS), 0, stream>>>(durs, text, out, B, T, tilesPerB, nwg);
}